// Round 6
// baseline (193.793 us; speedup 1.0000x reference)
//
#include <hip/hip_runtime.h>
#include <hip/hip_bf16.h>
#include <stdint.h>

#define NTOK 4096
#define DDIM 768
#define HDIM 1536
#define NEXP 6
#define NTYPE 32
#define PADROWS 4224

typedef __bf16 bf16x8 __attribute__((ext_vector_type(8)));
typedef float f32x4 __attribute__((ext_vector_type(4)));

static __device__ __forceinline__ unsigned short f2bf(float f) {
  union { float f; unsigned u; } v; v.f = f;
  unsigned r = v.u + 0x7FFFu + ((v.u >> 16) & 1u);
  return (unsigned short)(r >> 16);
}

static __device__ __forceinline__ void gload_lds16(const void* g, void* lds) {
  auto* g1 = reinterpret_cast<const __attribute__((address_space(1))) uint32_t*>(
      reinterpret_cast<uintptr_t>(g));
  auto* l3 = reinterpret_cast<__attribute__((address_space(3))) uint32_t*>(
      (uint32_t)reinterpret_cast<uintptr_t>(lds));
  __builtin_amdgcn_global_load_lds(g1, l3, 16, 0, 0);
}

// ---------------- prep: weight transpose+convert (z<12) + bucketing (z==12) ----
// z<6:  W1 expert z   [768][1536] f32 -> w1t [1536][768] bf16
// z<12: W2 expert z-6 [1536][768] f32 -> w2t [768][1536] bf16
// z==12, block (0,0): token bucketing (hist + tile table + scatter perm)
__global__ __launch_bounds__(256)
void prep_kernel(const float* __restrict__ W1, const float* __restrict__ W2,
                 unsigned short* __restrict__ w1t, unsigned short* __restrict__ w2t,
                 const int* __restrict__ ids, const int* __restrict__ ev2g,
                 int* __restrict__ perm, int* __restrict__ meta) {
  const int z = blockIdx.z;
  const int t = threadIdx.x;
  if (z == 12) {
    if (blockIdx.x != 0 || blockIdx.y != 0) return;
    __shared__ int s_ev2g[NTYPE];
    __shared__ int s_cnt[NEXP];
    __shared__ int s_off[NEXP];
    __shared__ int s_cur[NEXP];
    if (t < NTYPE) s_ev2g[t] = ev2g[t];
    if (t < NEXP) { s_cnt[t] = 0; s_cur[t] = 0; }
    __syncthreads();
    int g[16];
    #pragma unroll
    for (int i = 0; i < 16; ++i) {
      int idx = t * 16 + i;
      int ty = ids[idx];
      ty = ty < 0 ? 0 : (ty > NTYPE - 1 ? NTYPE - 1 : ty);
      g[i] = s_ev2g[ty];
      atomicAdd(&s_cnt[g[i]], 1);
    }
    __syncthreads();
    if (t == 0) {
      int off = 0, nt = 0;
      int* table = meta + 21;
      for (int e = 0; e < NEXP; ++e) {
        s_off[e] = off;
        int c = s_cnt[e];
        for (int k = 0; k * 128 < c; ++k) {
          int rem = c - k * 128;
          table[nt * 3 + 0] = e;
          table[nt * 3 + 1] = off + k * 128;
          table[nt * 3 + 2] = rem < 128 ? rem : 128;
          ++nt;
        }
        off += c;
      }
      meta[20] = nt;
    }
    __syncthreads();
    #pragma unroll
    for (int i = 0; i < 16; ++i) {
      int idx = t * 16 + i;
      int pos = s_off[g[i]] + atomicAdd(&s_cur[g[i]], 1);
      perm[pos] = idx;
    }
    return;
  }
  // ---- transpose path ----
  __shared__ float tile[64][65];
  const float* src;
  unsigned short* dst;
  int R, C, bx, by;
  if (z < 6) {
    src = W1 + (size_t)z * 768 * 1536; dst = w1t + (size_t)z * 768 * 1536;
    R = 768; C = 1536; bx = blockIdx.x; by = blockIdx.y;     // bx<24, by<12
  } else {
    src = W2 + (size_t)(z - 6) * 768 * 1536; dst = w2t + (size_t)(z - 6) * 768 * 1536;
    R = 1536; C = 768; bx = blockIdx.y; by = blockIdx.x;     // bx<12, by<24
  }
  const int r0 = by * 64, c0 = bx * 64;
  const int lr = t >> 4;           // 0..15
  const int lc = (t & 15) << 2;    // 0..60 step 4
  #pragma unroll
  for (int i = 0; i < 4; ++i) {
    float4 v = *reinterpret_cast<const float4*>(src + (size_t)(r0 + i * 16 + lr) * C + c0 + lc);
    tile[i * 16 + lr][lc]     = v.x;
    tile[i * 16 + lr][lc + 1] = v.y;
    tile[i * 16 + lr][lc + 2] = v.z;
    tile[i * 16 + lr][lc + 3] = v.w;
  }
  __syncthreads();
  const int l8 = (t & 7) << 3;     // 0..56 step 8
  #pragma unroll
  for (int p = 0; p < 2; ++p) {
    int j = p * 32 + (t >> 3);
    union { unsigned short u[8]; uint4 v; } pk;
    #pragma unroll
    for (int k = 0; k < 8; ++k) pk.u[k] = f2bf(tile[l8 + k][j]);
    *reinterpret_cast<uint4*>(dst + (size_t)(c0 + j) * R + r0 + l8) = pk.v;
  }
}

// gather x rows into permuted order, fp32 -> bf16. 1024 blocks x 256 (wave per row)
__global__ __launch_bounds__(256)
void xgather_kernel(const float* __restrict__ x, const int* __restrict__ perm,
                    unsigned short* __restrict__ xg) {
  const int wave = threadIdx.x >> 6, lane = threadIdx.x & 63;
  const int row = (blockIdx.x << 2) + wave;       // 4096
  const int src = perm[row];
  const float4* in = reinterpret_cast<const float4*>(x + (size_t)src * DDIM);
  ushort4* outp = reinterpret_cast<ushort4*>(xg + (size_t)row * DDIM);
  #pragma unroll
  for (int j = 0; j < 3; ++j) {
    float4 v = in[lane + j * 64];
    ushort4 o;
    o.x = f2bf(v.x); o.y = f2bf(v.y); o.z = f2bf(v.z); o.w = f2bf(v.w);
    outp[lane + j * 64] = o;
  }
}

// ---------------- grouped GEMM: 128x128 tile, 4 waves (2x2), 64x64/wave ----------------
// m97-shape fragments (4x4 per wave, ds_read:MFMA = 0.5) + round-2 pipeline
// (dbuf, stage-before-compute, single barrier/K-step). LDS XOR-swizzle via
// pre-swizzled global source (rule #21); reads apply the same XOR.
template <int K, int NT, bool PASS2>
__global__ __launch_bounds__(256, 2)
void gemm_kernel(const unsigned short* __restrict__ A,
                 const unsigned short* __restrict__ Bw,
                 const float* __restrict__ bias,      // [E][NT*128]
                 const int* __restrict__ meta,
                 const int* __restrict__ perm,
                 const float* __restrict__ x,         // [NTOK][DDIM]
                 const float* __restrict__ raw_alpha, // [E]
                 unsigned short* __restrict__ hout,   // pass1: [PADROWS][HDIM]
                 float* __restrict__ out)             // pass2: [NTOK][DDIM]
{
  constexpr int BM = 128, BN = 128;
  constexpr int NDIM = NT * BN;
  constexpr int NK = K / 64;

  // XCD-chunked bijective swizzle (nwg = 40*NT: 480 or 240, both %8==0)
  const int nwg = 40 * NT;
  const int q = nwg >> 3;
  const int vid = (blockIdx.x & 7) * q + (blockIdx.x >> 3);
  const int nt = vid / 40;       // nt-major: neighbors share B-panel
  const int mt = vid % 40;
  if (mt >= meta[20]) return;
  const int* table = meta + 21;
  const int e = table[mt * 3 + 0], base = table[mt * 3 + 1], cnt = table[mt * 3 + 2];

  __shared__ __align__(16) unsigned short As[2][BM * 64];
  __shared__ __align__(16) unsigned short Bs[2][BN * 64];

  const int tid = threadIdx.x;
  const int wave = tid >> 6, lane = tid & 63;
  const int wm = wave >> 1, wn = wave & 1;

  const unsigned short* Abase = A + (size_t)base * K;
  const unsigned short* Bbase = Bw + ((size_t)e * NDIM + (size_t)nt * BN) * K;

  f32x4 acc[4][4];
  #pragma unroll
  for (int i = 0; i < 4; ++i)
    #pragma unroll
    for (int j = 0; j < 4; ++j) acc[i][j] = (f32x4){0.f, 0.f, 0.f, 0.f};

  // staging: 16KB per operand per K-step = 4 chunks/thread (256 thr x 16B)
  int sRow[4], sElem[4], sLds[4];
  #pragma unroll
  for (int i = 0; i < 4; ++i) {
    int chunk = i * 256 + tid;
    int o = chunk * 16;
    int row = o >> 7;
    int inb = (o & 127) ^ ((row & 7) << 4);
    sRow[i] = row; sElem[i] = inb >> 1;
    sLds[i] = (i * 256 + wave * 64) * 16;        // wave-uniform dest base
  }

  // prologue: stage tile 0
  #pragma unroll
  for (int i = 0; i < 4; ++i)
    gload_lds16(Abase + (size_t)sRow[i] * K + sElem[i], (char*)As[0] + sLds[i]);
  #pragma unroll
  for (int i = 0; i < 4; ++i)
    gload_lds16(Bbase + (size_t)sRow[i] * K + sElem[i], (char*)Bs[0] + sLds[i]);
  __syncthreads();

  int cur = 0;
  for (int kt = 0; kt < NK; ++kt) {
    if (kt + 1 < NK) {               // issue next-tile loads BEFORE compute
      const int k0 = (kt + 1) * 64;
      #pragma unroll
      for (int i = 0; i < 4; ++i)
        gload_lds16(Abase + (size_t)sRow[i] * K + k0 + sElem[i], (char*)As[cur ^ 1] + sLds[i]);
      #pragma unroll
      for (int i = 0; i < 4; ++i)
        gload_lds16(Bbase + (size_t)sRow[i] * K + k0 + sElem[i], (char*)Bs[cur ^ 1] + sLds[i]);
    }
    #pragma unroll
    for (int ks = 0; ks < 2; ++ks) {
      bf16x8 av[4], bv[4];
      const int kb = ks * 64 + ((lane >> 4) << 4);
      #pragma unroll
      for (int mi = 0; mi < 4; ++mi) {
        int row = wm * 64 + mi * 16 + (lane & 15);
        int byte = (row * 128 + kb) ^ ((row & 7) << 4);
        av[mi] = *reinterpret_cast<const bf16x8*>((const char*)As[cur] + byte);
      }
      #pragma unroll
      for (int nj = 0; nj < 4; ++nj) {
        int row = wn * 64 + nj * 16 + (lane & 15);
        int byte = (row * 128 + kb) ^ ((row & 7) << 4);
        bv[nj] = *reinterpret_cast<const bf16x8*>((const char*)Bs[cur] + byte);
      }
      #pragma unroll
      for (int mi = 0; mi < 4; ++mi)
        #pragma unroll
        for (int nj = 0; nj < 4; ++nj)
          acc[mi][nj] = __builtin_amdgcn_mfma_f32_16x16x32_bf16(av[mi], bv[nj], acc[mi][nj], 0, 0, 0);
    }
    __syncthreads();                 // drains vmcnt (next tile landed) + buffer reuse
    cur ^= 1;
  }

  // epilogue. C/D layout: col = lane&15, row = (lane>>4)*4 + reg
  const int col0 = nt * BN + wn * 64;
  if constexpr (!PASS2) {
    #pragma unroll
    for (int nj = 0; nj < 4; ++nj) {
      int n = col0 + nj * 16 + (lane & 15);
      float bv = bias[e * NDIM + n];
      #pragma unroll
      for (int mi = 0; mi < 4; ++mi) {
        int rbase = wm * 64 + mi * 16 + ((lane >> 4) << 2);
        #pragma unroll
        for (int r = 0; r < 4; ++r) {
          int row = rbase + r;
          if (row < cnt) {
            float v = fmaxf(acc[mi][nj][r] + bv, 0.0f);
            hout[(size_t)(base + row) * NDIM + n] = f2bf(v);
          }
        }
      }
    }
  } else {
    float alpha = 0.05f / (1.0f + expf(-raw_alpha[e]));
    #pragma unroll
    for (int nj = 0; nj < 4; ++nj) {
      int n = col0 + nj * 16 + (lane & 15);
      float bv = bias[e * NDIM + n];
      #pragma unroll
      for (int mi = 0; mi < 4; ++mi) {
        int rbase = wm * 64 + mi * 16 + ((lane >> 4) << 2);
        #pragma unroll
        for (int r = 0; r < 4; ++r) {
          int row = rbase + r;
          if (row < cnt) {
            int tok = perm[base + row];
            size_t oi = (size_t)tok * DDIM + n;
            out[oi] = x[oi] + alpha * (acc[mi][nj][r] + bv);
          }
        }
      }
    }
  }
}

// L2-normalize each 768-row of out in place; one wave per token
__global__ __launch_bounds__(256)
void norm_kernel(float* __restrict__ out) {
  const int wave = threadIdx.x >> 6, lane = threadIdx.x & 63;
  const int tok = (blockIdx.x << 2) + wave;
  float4* p = reinterpret_cast<float4*>(out) + (size_t)tok * 192;
  float4 a = p[lane], b = p[lane + 64], c = p[lane + 128];
  float ss = a.x * a.x + a.y * a.y + a.z * a.z + a.w * a.w
           + b.x * b.x + b.y * b.y + b.z * b.z + b.w * b.w
           + c.x * c.x + c.y * c.y + c.z * c.z + c.w * c.w;
  #pragma unroll
  for (int off = 32; off; off >>= 1) ss += __shfl_xor(ss, off);
  const float s = 1.0f / fmaxf(sqrtf(ss), 1e-12f);
  a.x *= s; a.y *= s; a.z *= s; a.w *= s;
  b.x *= s; b.y *= s; b.z *= s; b.w *= s;
  c.x *= s; c.y *= s; c.z *= s; c.w *= s;
  p[lane] = a; p[lane + 64] = b; p[lane + 128] = c;
}

// ---------------- launch ----------------

extern "C" void kernel_launch(void* const* d_in, const int* in_sizes, int n_in,
                              void* d_out, int out_size, void* d_ws, size_t ws_size,
                              hipStream_t stream) {
  const float* x      = (const float*)d_in[0];
  const int*   ids    = (const int*)d_in[1];
  const float* W1     = (const float*)d_in[2];
  const float* b1     = (const float*)d_in[3];
  const float* W2     = (const float*)d_in[4];
  const float* b2     = (const float*)d_in[5];
  const float* ralpha = (const float*)d_in[6];
  const int*   ev2g   = (const int*)d_in[7];
  float* out = (float*)d_out;
  char* ws = (char*)d_ws;

  unsigned short* w1t = (unsigned short*)(ws);                 // [6][1536][768] bf16
  unsigned short* w2t = (unsigned short*)(ws + 14155776);      // [6][768][1536] bf16
  unsigned short* xg  = (unsigned short*)(ws + 28311552);      // [4224][768]  bf16
  unsigned short* h   = (unsigned short*)(ws + 34799616);      // [4224][1536] bf16
  int* perm = (int*)(ws + 47775744);
  int* meta = (int*)(ws + 47808512);

  prep_kernel<<<dim3(24, 12, 13), 256, 0, stream>>>(W1, W2, w1t, w2t, ids, ev2g, perm, meta);
  xgather_kernel<<<1024, 256, 0, stream>>>(x, perm, xg);
  // pass1: h = relu(xg @ W1 + b1)   M=4096 grouped, N=1536, K=768
  gemm_kernel<DDIM, 12, false><<<480, 256, 0, stream>>>(
      xg, w1t, b1, meta, perm, x, ralpha, h, out);
  // pass2: out = x + alpha*(h @ W2 + b2)  M=4096 grouped, N=768, K=1536
  gemm_kernel<HDIM, 6, true><<<240, 256, 0, stream>>>(
      h, w2t, b2, meta, perm, x, ralpha, nullptr, out);
  norm_kernel<<<1024, 256, 0, stream>>>(out);
}

// Round 8
// 186.223 us; speedup vs baseline: 1.0406x; 1.0406x over previous
//
#include <hip/hip_runtime.h>
#include <hip/hip_bf16.h>
#include <stdint.h>

#define NTOK 4096
#define DDIM 768
#define HDIM 1536
#define NEXP 6
#define NTYPE 32
#define PADROWS 4224
#define MAXTILES 70   // 64-row granularity: sum ceil(c_e/64) <= 4096/64 + 6 = 70

typedef __bf16 bf16x8 __attribute__((ext_vector_type(8)));
typedef float f32x4 __attribute__((ext_vector_type(4)));

static __device__ __forceinline__ unsigned short f2bf(float f) {
  union { float f; unsigned u; } v; v.f = f;
  unsigned r = v.u + 0x7FFFu + ((v.u >> 16) & 1u);
  return (unsigned short)(r >> 16);
}

static __device__ __forceinline__ void gload_lds16(const void* g, void* lds) {
  auto* g1 = reinterpret_cast<const __attribute__((address_space(1))) uint32_t*>(
      reinterpret_cast<uintptr_t>(g));
  auto* l3 = reinterpret_cast<__attribute__((address_space(3))) uint32_t*>(
      (uint32_t)reinterpret_cast<uintptr_t>(lds));
  __builtin_amdgcn_global_load_lds(g1, l3, 16, 0, 0);
}

// ---------------- prep: weight transpose+convert (z<12) + bucketing (z==12) ----
__global__ __launch_bounds__(256)
void prep_kernel(const float* __restrict__ W1, const float* __restrict__ W2,
                 unsigned short* __restrict__ w1t, unsigned short* __restrict__ w2t,
                 const int* __restrict__ ids, const int* __restrict__ ev2g,
                 int* __restrict__ perm, int* __restrict__ meta) {
  const int z = blockIdx.z;
  const int t = threadIdx.x;
  if (z == 12) {
    if (blockIdx.x != 0 || blockIdx.y != 0) return;
    __shared__ int s_ev2g[NTYPE];
    __shared__ int s_cnt[NEXP];
    __shared__ int s_off[NEXP];
    __shared__ int s_cur[NEXP];
    if (t < NTYPE) s_ev2g[t] = ev2g[t];
    if (t < NEXP) { s_cnt[t] = 0; s_cur[t] = 0; }
    __syncthreads();
    int g[16];
    #pragma unroll
    for (int i = 0; i < 16; ++i) {
      int idx = t * 16 + i;
      int ty = ids[idx];
      ty = ty < 0 ? 0 : (ty > NTYPE - 1 ? NTYPE - 1 : ty);
      g[i] = s_ev2g[ty];
      atomicAdd(&s_cnt[g[i]], 1);
    }
    __syncthreads();
    if (t == 0) {
      int off = 0, nt = 0;
      int* table = meta + 21;
      for (int e = 0; e < NEXP; ++e) {
        s_off[e] = off;
        int c = s_cnt[e];
        for (int k = 0; k * 64 < c; ++k) {     // 64-row tiles
          int rem = c - k * 64;
          table[nt * 3 + 0] = e;
          table[nt * 3 + 1] = off + k * 64;
          table[nt * 3 + 2] = rem < 64 ? rem : 64;
          ++nt;
        }
        off += c;
      }
      meta[20] = nt;
    }
    __syncthreads();
    #pragma unroll
    for (int i = 0; i < 16; ++i) {
      int idx = t * 16 + i;
      int pos = s_off[g[i]] + atomicAdd(&s_cur[g[i]], 1);
      perm[pos] = idx;
    }
    return;
  }
  // ---- transpose path ----
  __shared__ float tile[64][65];
  const float* src;
  unsigned short* dst;
  int R, C, bx, by;
  if (z < 6) {
    src = W1 + (size_t)z * 768 * 1536; dst = w1t + (size_t)z * 768 * 1536;
    R = 768; C = 1536; bx = blockIdx.x; by = blockIdx.y;     // bx<24, by<12
  } else {
    src = W2 + (size_t)(z - 6) * 768 * 1536; dst = w2t + (size_t)(z - 6) * 768 * 1536;
    R = 1536; C = 768; bx = blockIdx.y; by = blockIdx.x;     // bx<12, by<24
  }
  const int r0 = by * 64, c0 = bx * 64;
  const int lr = t >> 4;
  const int lc = (t & 15) << 2;
  #pragma unroll
  for (int i = 0; i < 4; ++i) {
    float4 v = *reinterpret_cast<const float4*>(src + (size_t)(r0 + i * 16 + lr) * C + c0 + lc);
    tile[i * 16 + lr][lc]     = v.x;
    tile[i * 16 + lr][lc + 1] = v.y;
    tile[i * 16 + lr][lc + 2] = v.z;
    tile[i * 16 + lr][lc + 3] = v.w;
  }
  __syncthreads();
  const int l8 = (t & 7) << 3;
  #pragma unroll
  for (int p = 0; p < 2; ++p) {
    int j = p * 32 + (t >> 3);
    union { unsigned short u[8]; uint4 v; } pk;
    #pragma unroll
    for (int k = 0; k < 8; ++k) pk.u[k] = f2bf(tile[l8 + k][j]);
    *reinterpret_cast<uint4*>(dst + (size_t)(c0 + j) * R + r0 + l8) = pk.v;
  }
}

// gather x rows into permuted order, fp32 -> bf16 (wave per row)
__global__ __launch_bounds__(256)
void xgather_kernel(const float* __restrict__ x, const int* __restrict__ perm,
                    unsigned short* __restrict__ xg) {
  const int wave = threadIdx.x >> 6, lane = threadIdx.x & 63;
  const int row = (blockIdx.x << 2) + wave;       // 4096
  const int src = perm[row];
  const float4* in = reinterpret_cast<const float4*>(x + (size_t)src * DDIM);
  ushort4* outp = reinterpret_cast<ushort4*>(xg + (size_t)row * DDIM);
  #pragma unroll
  for (int j = 0; j < 3; ++j) {
    float4 v = in[lane + j * 64];
    ushort4 o;
    o.x = f2bf(v.x); o.y = f2bf(v.y); o.z = f2bf(v.z); o.w = f2bf(v.w);
    outp[lane + j * 64] = o;
  }
}

// ---------------- grouped GEMM: 64x128 tile, BK=64, 4 waves (2x2), 32x64/wave ----
// Small-M tiles -> grid 840/420 blocks; 48KB LDS dbuf -> 3 blocks/CU. Round-2
// pipeline (stage-next-before-compute, one barrier/K-step). XOR-swizzle
// ((row&7)<<4) via pre-swizzled global source (rule #21); reads apply same XOR.
template <int K, int NT, bool PASS2>
__global__ __launch_bounds__(256, 3)
void gemm_kernel(const unsigned short* __restrict__ A,
                 const unsigned short* __restrict__ Bw,
                 const float* __restrict__ bias,      // [E][NT*128]
                 const int* __restrict__ meta,
                 const int* __restrict__ perm,
                 const float* __restrict__ x,         // [NTOK][DDIM]
                 const float* __restrict__ raw_alpha, // [E]
                 unsigned short* __restrict__ hout,   // pass1: [PADROWS][HDIM]
                 float* __restrict__ out)             // pass2: [NTOK][DDIM]
{
  constexpr int BM = 64, BN = 128;
  constexpr int NDIM = NT * BN;
  constexpr int NK = K / 64;

  // bijective XCD-chunked swizzle (m204 form; works for nwg % 8 != 0)
  const int nwg = MAXTILES * NT;
  const int q = nwg >> 3, r = nwg & 7;
  const int x8 = blockIdx.x & 7;
  const int o8 = blockIdx.x >> 3;
  const int vid = (x8 < r ? x8 * (q + 1) : r * (q + 1) + (x8 - r) * q) + o8;
  const int nt = vid / MAXTILES;   // nt-major: neighbors share B-panel (L2)
  const int mt = vid % MAXTILES;
  if (mt >= meta[20]) return;
  const int* table = meta + 21;
  const int e = table[mt * 3 + 0], base = table[mt * 3 + 1], cnt = table[mt * 3 + 2];

  __shared__ __align__(16) unsigned short As[2][BM * 64];
  __shared__ __align__(16) unsigned short Bs[2][BN * 64];

  const int tid = threadIdx.x;
  const int wave = tid >> 6, lane = tid & 63;
  const int wm = wave >> 1, wn = wave & 1;

  const unsigned short* Abase = A + (size_t)base * K;
  const unsigned short* Bbase = Bw + ((size_t)e * NDIM + (size_t)nt * BN) * K;

  f32x4 acc[2][4];
  #pragma unroll
  for (int i = 0; i < 2; ++i)
    #pragma unroll
    for (int j = 0; j < 4; ++j) acc[i][j] = (f32x4){0.f, 0.f, 0.f, 0.f};

  // staging: A 8KB (2 chunks/thread), B 16KB (4 chunks/thread); 128B LDS rows
  int aRow[2], aElem[2], aLds[2];
  #pragma unroll
  for (int i = 0; i < 2; ++i) {
    int chunk = i * 256 + tid;
    int o = chunk * 16;
    int row = o >> 7;
    int inb = (o & 127) ^ ((row & 7) << 4);
    aRow[i] = row; aElem[i] = inb >> 1;
    aLds[i] = (i * 256 + wave * 64) * 16;
  }
  int bRow[4], bElem[4], bLds[4];
  #pragma unroll
  for (int i = 0; i < 4; ++i) {
    int chunk = i * 256 + tid;
    int o = chunk * 16;
    int row = o >> 7;
    int inb = (o & 127) ^ ((row & 7) << 4);
    bRow[i] = row; bElem[i] = inb >> 1;
    bLds[i] = (i * 256 + wave * 64) * 16;
  }

  // prologue: stage tile 0
  #pragma unroll
  for (int i = 0; i < 2; ++i)
    gload_lds16(Abase + (size_t)aRow[i] * K + aElem[i], (char*)As[0] + aLds[i]);
  #pragma unroll
  for (int i = 0; i < 4; ++i)
    gload_lds16(Bbase + (size_t)bRow[i] * K + bElem[i], (char*)Bs[0] + bLds[i]);
  __syncthreads();

  int cur = 0;
  for (int kt = 0; kt < NK; ++kt) {
    if (kt + 1 < NK) {               // issue next-tile loads BEFORE compute
      const int k0 = (kt + 1) * 64;
      #pragma unroll
      for (int i = 0; i < 2; ++i)
        gload_lds16(Abase + (size_t)aRow[i] * K + k0 + aElem[i], (char*)As[cur ^ 1] + aLds[i]);
      #pragma unroll
      for (int i = 0; i < 4; ++i)
        gload_lds16(Bbase + (size_t)bRow[i] * K + k0 + bElem[i], (char*)Bs[cur ^ 1] + bLds[i]);
    }
    #pragma unroll
    for (int ks = 0; ks < 2; ++ks) {
      bf16x8 av[2], bv[4];
      const int kb = ks * 64 + ((lane >> 4) << 4);
      #pragma unroll
      for (int mi = 0; mi < 2; ++mi) {
        int row = wm * 32 + mi * 16 + (lane & 15);
        int byte = (row * 128 + kb) ^ ((row & 7) << 4);
        av[mi] = *reinterpret_cast<const bf16x8*>((const char*)As[cur] + byte);
      }
      #pragma unroll
      for (int nj = 0; nj < 4; ++nj) {
        int row = wn * 64 + nj * 16 + (lane & 15);
        int byte = (row * 128 + kb) ^ ((row & 7) << 4);
        bv[nj] = *reinterpret_cast<const bf16x8*>((const char*)Bs[cur] + byte);
      }
      #pragma unroll
      for (int mi = 0; mi < 2; ++mi)
        #pragma unroll
        for (int nj = 0; nj < 4; ++nj)
          acc[mi][nj] = __builtin_amdgcn_mfma_f32_16x16x32_bf16(av[mi], bv[nj], acc[mi][nj], 0, 0, 0);
    }
    __syncthreads();                 // drains vmcnt (next tile landed) + buffer reuse
    cur ^= 1;
  }

  // epilogue. C/D layout: col = lane&15, row = (lane>>4)*4 + reg
  const int col0 = nt * BN + wn * 64;
  if constexpr (!PASS2) {
    #pragma unroll
    for (int nj = 0; nj < 4; ++nj) {
      int n = col0 + nj * 16 + (lane & 15);
      float bv = bias[e * NDIM + n];
      #pragma unroll
      for (int mi = 0; mi < 2; ++mi) {
        int rbase = wm * 32 + mi * 16 + ((lane >> 4) << 2);
        #pragma unroll
        for (int rr = 0; rr < 4; ++rr) {
          int row = rbase + rr;
          if (row < cnt) {
            float v = fmaxf(acc[mi][nj][rr] + bv, 0.0f);
            hout[(size_t)(base + row) * NDIM + n] = f2bf(v);
          }
        }
      }
    }
  } else {
    float alpha = 0.05f / (1.0f + expf(-raw_alpha[e]));
    #pragma unroll
    for (int nj = 0; nj < 4; ++nj) {
      int n = col0 + nj * 16 + (lane & 15);
      float bv = bias[e * NDIM + n];
      #pragma unroll
      for (int mi = 0; mi < 2; ++mi) {
        int rbase = wm * 32 + mi * 16 + ((lane >> 4) << 2);
        #pragma unroll
        for (int rr = 0; rr < 4; ++rr) {
          int row = rbase + rr;
          if (row < cnt) {
            int tok = perm[base + row];
            size_t oi = (size_t)tok * DDIM + n;
            out[oi] = x[oi] + alpha * (acc[mi][nj][rr] + bv);
          }
        }
      }
    }
  }
}

// L2-normalize each 768-row of out in place; one wave per token
__global__ __launch_bounds__(256)
void norm_kernel(float* __restrict__ out) {
  const int wave = threadIdx.x >> 6, lane = threadIdx.x & 63;
  const int tok = (blockIdx.x << 2) + wave;
  float4* p = reinterpret_cast<float4*>(out) + (size_t)tok * 192;
  float4 a = p[lane], b = p[lane + 64], c = p[lane + 128];
  float ss = a.x * a.x + a.y * a.y + a.z * a.z + a.w * a.w
           + b.x * b.x + b.y * b.y + b.z * b.z + b.w * b.w
           + c.x * c.x + c.y * c.y + c.z * c.z + c.w * c.w;
  #pragma unroll
  for (int off = 32; off; off >>= 1) ss += __shfl_xor(ss, off);
  const float s = 1.0f / fmaxf(sqrtf(ss), 1e-12f);
  a.x *= s; a.y *= s; a.z *= s; a.w *= s;
  b.x *= s; b.y *= s; b.z *= s; b.w *= s;
  c.x *= s; c.y *= s; c.z *= s; c.w *= s;
  p[lane] = a; p[lane + 64] = b; p[lane + 128] = c;
}

// ---------------- launch ----------------

extern "C" void kernel_launch(void* const* d_in, const int* in_sizes, int n_in,
                              void* d_out, int out_size, void* d_ws, size_t ws_size,
                              hipStream_t stream) {
  const float* x      = (const float*)d_in[0];
  const int*   ids    = (const int*)d_in[1];
  const float* W1     = (const float*)d_in[2];
  const float* b1     = (const float*)d_in[3];
  const float* W2     = (const float*)d_in[4];
  const float* b2     = (const float*)d_in[5];
  const float* ralpha = (const float*)d_in[6];
  const int*   ev2g   = (const int*)d_in[7];
  float* out = (float*)d_out;
  char* ws = (char*)d_ws;

  unsigned short* w1t = (unsigned short*)(ws);                 // [6][1536][768] bf16
  unsigned short* w2t = (unsigned short*)(ws + 14155776);      // [6][768][1536] bf16
  unsigned short* xg  = (unsigned short*)(ws + 28311552);      // [4224][768]  bf16
  unsigned short* h   = (unsigned short*)(ws + 34799616);      // [4224][1536] bf16
  int* perm = (int*)(ws + 47775744);
  int* meta = (int*)(ws + 47808512);

  prep_kernel<<<dim3(24, 12, 13), 256, 0, stream>>>(W1, W2, w1t, w2t, ids, ev2g, perm, meta);
  xgather_kernel<<<1024, 256, 0, stream>>>(x, perm, xg);
  // pass1: h = relu(xg @ W1 + b1)   M=4096 grouped, N=1536, K=768
  gemm_kernel<DDIM, 12, false><<<MAXTILES * 12, 256, 0, stream>>>(
      xg, w1t, b1, meta, perm, x, ralpha, h, out);
  // pass2: out = x + alpha*(h @ W2 + b2)  M=4096 grouped, N=768, K=1536
  gemm_kernel<HDIM, 6, true><<<MAXTILES * 6, 256, 0, stream>>>(
      h, w2t, b2, meta, perm, x, ralpha, nullptr, out);
  norm_kernel<<<1024, 256, 0, stream>>>(out);
}

// Round 9
// 185.027 us; speedup vs baseline: 1.0474x; 1.0065x over previous
//
#include <hip/hip_runtime.h>
#include <hip/hip_bf16.h>
#include <stdint.h>

#define NTOK 4096
#define DDIM 768
#define HDIM 1536
#define NEXP 6
#define NTYPE 32
#define PADROWS 4224
#define MAXTILES 70   // 64-row granularity: sum ceil(c_e/64) <= 4096/64 + 6 = 70

typedef __bf16 bf16x8 __attribute__((ext_vector_type(8)));
typedef float f32x4 __attribute__((ext_vector_type(4)));

static __device__ __forceinline__ unsigned short f2bf(float f) {
  union { float f; unsigned u; } v; v.f = f;
  unsigned r = v.u + 0x7FFFu + ((v.u >> 16) & 1u);
  return (unsigned short)(r >> 16);
}

static __device__ __forceinline__ void gload_lds16(const void* g, void* lds) {
  auto* g1 = reinterpret_cast<const __attribute__((address_space(1))) uint32_t*>(
      reinterpret_cast<uintptr_t>(g));
  auto* l3 = reinterpret_cast<__attribute__((address_space(3))) uint32_t*>(
      (uint32_t)reinterpret_cast<uintptr_t>(lds));
  __builtin_amdgcn_global_load_lds(g1, l3, 16, 0, 0);
}

// ---------------- prep: weight transpose+convert (z<12) + bucketing (z==12) ----
__global__ __launch_bounds__(256)
void prep_kernel(const float* __restrict__ W1, const float* __restrict__ W2,
                 unsigned short* __restrict__ w1t, unsigned short* __restrict__ w2t,
                 const int* __restrict__ ids, const int* __restrict__ ev2g,
                 int* __restrict__ perm, int* __restrict__ meta) {
  const int z = blockIdx.z;
  const int t = threadIdx.x;
  if (z == 12) {
    if (blockIdx.x != 0 || blockIdx.y != 0) return;
    __shared__ int s_ev2g[NTYPE];
    __shared__ int s_cnt[NEXP];
    __shared__ int s_off[NEXP];
    __shared__ int s_cur[NEXP];
    if (t < NTYPE) s_ev2g[t] = ev2g[t];
    if (t < NEXP) { s_cnt[t] = 0; s_cur[t] = 0; }
    __syncthreads();
    int g[16];
    #pragma unroll
    for (int i = 0; i < 16; ++i) {
      int idx = t * 16 + i;
      int ty = ids[idx];
      ty = ty < 0 ? 0 : (ty > NTYPE - 1 ? NTYPE - 1 : ty);
      g[i] = s_ev2g[ty];
      atomicAdd(&s_cnt[g[i]], 1);
    }
    __syncthreads();
    if (t == 0) {
      int off = 0, nt = 0;
      int* table = meta + 21;
      for (int e = 0; e < NEXP; ++e) {
        s_off[e] = off;
        int c = s_cnt[e];
        for (int k = 0; k * 64 < c; ++k) {     // 64-row tiles
          int rem = c - k * 64;
          table[nt * 3 + 0] = e;
          table[nt * 3 + 1] = off + k * 64;
          table[nt * 3 + 2] = rem < 64 ? rem : 64;
          ++nt;
        }
        off += c;
      }
      meta[20] = nt;
    }
    __syncthreads();
    #pragma unroll
    for (int i = 0; i < 16; ++i) {
      int idx = t * 16 + i;
      int pos = s_off[g[i]] + atomicAdd(&s_cur[g[i]], 1);
      perm[pos] = idx;
    }
    return;
  }
  // ---- transpose path ----
  __shared__ float tile[64][65];
  const float* src;
  unsigned short* dst;
  int R, C, bx, by;
  if (z < 6) {
    src = W1 + (size_t)z * 768 * 1536; dst = w1t + (size_t)z * 768 * 1536;
    R = 768; C = 1536; bx = blockIdx.x; by = blockIdx.y;     // bx<24, by<12
  } else {
    src = W2 + (size_t)(z - 6) * 768 * 1536; dst = w2t + (size_t)(z - 6) * 768 * 1536;
    R = 1536; C = 768; bx = blockIdx.y; by = blockIdx.x;     // bx<12, by<24
  }
  const int r0 = by * 64, c0 = bx * 64;
  const int lr = t >> 4;
  const int lc = (t & 15) << 2;
  #pragma unroll
  for (int i = 0; i < 4; ++i) {
    float4 v = *reinterpret_cast<const float4*>(src + (size_t)(r0 + i * 16 + lr) * C + c0 + lc);
    tile[i * 16 + lr][lc]     = v.x;
    tile[i * 16 + lr][lc + 1] = v.y;
    tile[i * 16 + lr][lc + 2] = v.z;
    tile[i * 16 + lr][lc + 3] = v.w;
  }
  __syncthreads();
  const int l8 = (t & 7) << 3;
  #pragma unroll
  for (int p = 0; p < 2; ++p) {
    int j = p * 32 + (t >> 3);
    union { unsigned short u[8]; uint4 v; } pk;
    #pragma unroll
    for (int k = 0; k < 8; ++k) pk.u[k] = f2bf(tile[l8 + k][j]);
    *reinterpret_cast<uint4*>(dst + (size_t)(c0 + j) * R + r0 + l8) = pk.v;
  }
}

// gather x rows into permuted order, fp32 -> bf16 (wave per row)
__global__ __launch_bounds__(256)
void xgather_kernel(const float* __restrict__ x, const int* __restrict__ perm,
                    unsigned short* __restrict__ xg) {
  const int wave = threadIdx.x >> 6, lane = threadIdx.x & 63;
  const int row = (blockIdx.x << 2) + wave;       // 4096
  const int src = perm[row];
  const float4* in = reinterpret_cast<const float4*>(x + (size_t)src * DDIM);
  ushort4* outp = reinterpret_cast<ushort4*>(xg + (size_t)row * DDIM);
  #pragma unroll
  for (int j = 0; j < 3; ++j) {
    float4 v = in[lane + j * 64];
    ushort4 o;
    o.x = f2bf(v.x); o.y = f2bf(v.y); o.z = f2bf(v.z); o.w = f2bf(v.w);
    outp[lane + j * 64] = o;
  }
}

// ---------------- grouped GEMM: 64x128 tile, BK=64, 4 waves (2x2), 32x64/wave ----
// Depth-2 prefetch pipeline (T3/T4-lite, m201 pattern): 3 LDS buffers, counted
// vmcnt (12 = 2 tiles x 6 loads/thread in flight, peeled tail 6/0), raw
// s_barrier (no vmcnt(0) drain). 72KB LDS -> 2 blocks/CU. XOR-swizzle
// ((row&7)<<4) via pre-swizzled global source (rule #21); reads apply same XOR.
template <int K, int NT, bool PASS2>
__global__ __launch_bounds__(256, 2)
void gemm_kernel(const unsigned short* __restrict__ A,
                 const unsigned short* __restrict__ Bw,
                 const float* __restrict__ bias,      // [E][NT*128]
                 const int* __restrict__ meta,
                 const int* __restrict__ perm,
                 const float* __restrict__ x,         // [NTOK][DDIM]
                 const float* __restrict__ raw_alpha, // [E]
                 unsigned short* __restrict__ hout,   // pass1: [PADROWS][HDIM]
                 float* __restrict__ out)             // pass2: [NTOK][DDIM]
{
  constexpr int BM = 64, BN = 128;
  constexpr int NDIM = NT * BN;
  constexpr int NK = K / 64;

  // bijective XCD-chunked swizzle (m204 form; works for nwg % 8 != 0)
  const int nwg = MAXTILES * NT;
  const int q = nwg >> 3, r = nwg & 7;
  const int x8 = blockIdx.x & 7;
  const int o8 = blockIdx.x >> 3;
  const int vid = (x8 < r ? x8 * (q + 1) : r * (q + 1) + (x8 - r) * q) + o8;
  const int nt = vid / MAXTILES;   // nt-major: neighbors share B-panel (L2)
  const int mt = vid % MAXTILES;
  if (mt >= meta[20]) return;
  const int* table = meta + 21;
  const int e = table[mt * 3 + 0], base = table[mt * 3 + 1], cnt = table[mt * 3 + 2];

  __shared__ __align__(16) unsigned short As[3][BM * 64];
  __shared__ __align__(16) unsigned short Bs[3][BN * 64];

  const int tid = threadIdx.x;
  const int wave = tid >> 6, lane = tid & 63;
  const int wm = wave >> 1, wn = wave & 1;

  const unsigned short* Abase = A + (size_t)base * K;
  const unsigned short* Bbase = Bw + ((size_t)e * NDIM + (size_t)nt * BN) * K;

  f32x4 acc[2][4];
  #pragma unroll
  for (int i = 0; i < 2; ++i)
    #pragma unroll
    for (int j = 0; j < 4; ++j) acc[i][j] = (f32x4){0.f, 0.f, 0.f, 0.f};

  // staging: A 8KB (2 chunks/thread), B 16KB (4 chunks/thread); 128B LDS rows
  int aRow[2], aElem[2], aLds[2];
  #pragma unroll
  for (int i = 0; i < 2; ++i) {
    int chunk = i * 256 + tid;
    int o = chunk * 16;
    int row = o >> 7;
    int inb = (o & 127) ^ ((row & 7) << 4);
    aRow[i] = row; aElem[i] = inb >> 1;
    aLds[i] = (i * 256 + wave * 64) * 16;
  }
  int bRow[4], bElem[4], bLds[4];
  #pragma unroll
  for (int i = 0; i < 4; ++i) {
    int chunk = i * 256 + tid;
    int o = chunk * 16;
    int row = o >> 7;
    int inb = (o & 127) ^ ((row & 7) << 4);
    bRow[i] = row; bElem[i] = inb >> 1;
    bLds[i] = (i * 256 + wave * 64) * 16;
  }

  auto stage = [&](int kt, int buf) {
    const int k0 = kt * 64;
    #pragma unroll
    for (int i = 0; i < 2; ++i)
      gload_lds16(Abase + (size_t)aRow[i] * K + k0 + aElem[i], (char*)As[buf] + aLds[i]);
    #pragma unroll
    for (int i = 0; i < 4; ++i)
      gload_lds16(Bbase + (size_t)bRow[i] * K + k0 + bElem[i], (char*)Bs[buf] + bLds[i]);
  };

  // prologue: stage tiles 0,1 into buffers 0,1
  stage(0, 0);
  stage(1, 1);

  int get = 0, put = 2;
  for (int kt = 0; kt < NK; ++kt) {
    if (kt + 2 < NK) stage(kt + 2, put);     // keep 2 tiles in flight
    __builtin_amdgcn_sched_barrier(0);
    if (kt + 2 < NK)      asm volatile("s_waitcnt vmcnt(12)" ::: "memory");
    else if (kt + 1 < NK) asm volatile("s_waitcnt vmcnt(6)" ::: "memory");
    else                  asm volatile("s_waitcnt vmcnt(0)" ::: "memory");
    __builtin_amdgcn_s_barrier();            // all waves' buf[get] chunks landed
    __builtin_amdgcn_sched_barrier(0);
    #pragma unroll
    for (int ks = 0; ks < 2; ++ks) {
      bf16x8 av[2], bv[4];
      const int kb = ks * 64 + ((lane >> 4) << 4);
      #pragma unroll
      for (int mi = 0; mi < 2; ++mi) {
        int row = wm * 32 + mi * 16 + (lane & 15);
        int byte = (row * 128 + kb) ^ ((row & 7) << 4);
        av[mi] = *reinterpret_cast<const bf16x8*>((const char*)As[get] + byte);
      }
      #pragma unroll
      for (int nj = 0; nj < 4; ++nj) {
        int row = wn * 64 + nj * 16 + (lane & 15);
        int byte = (row * 128 + kb) ^ ((row & 7) << 4);
        bv[nj] = *reinterpret_cast<const bf16x8*>((const char*)Bs[get] + byte);
      }
      #pragma unroll
      for (int mi = 0; mi < 2; ++mi)
        #pragma unroll
        for (int nj = 0; nj < 4; ++nj)
          acc[mi][nj] = __builtin_amdgcn_mfma_f32_16x16x32_bf16(av[mi], bv[nj], acc[mi][nj], 0, 0, 0);
    }
    __builtin_amdgcn_sched_barrier(0);
    __builtin_amdgcn_s_barrier();            // reads of buf[get] done -> reusable
    get = (get == 2) ? 0 : get + 1;
    put = (put == 2) ? 0 : put + 1;
  }

  // epilogue. C/D layout: col = lane&15, row = (lane>>4)*4 + reg
  const int col0 = nt * BN + wn * 64;
  if constexpr (!PASS2) {
    #pragma unroll
    for (int nj = 0; nj < 4; ++nj) {
      int n = col0 + nj * 16 + (lane & 15);
      float bv = bias[e * NDIM + n];
      #pragma unroll
      for (int mi = 0; mi < 2; ++mi) {
        int rbase = wm * 32 + mi * 16 + ((lane >> 4) << 2);
        #pragma unroll
        for (int rr = 0; rr < 4; ++rr) {
          int row = rbase + rr;
          if (row < cnt) {
            float v = fmaxf(acc[mi][nj][rr] + bv, 0.0f);
            hout[(size_t)(base + row) * NDIM + n] = f2bf(v);
          }
        }
      }
    }
  } else {
    float alpha = 0.05f / (1.0f + expf(-raw_alpha[e]));
    #pragma unroll
    for (int nj = 0; nj < 4; ++nj) {
      int n = col0 + nj * 16 + (lane & 15);
      float bv = bias[e * NDIM + n];
      #pragma unroll
      for (int mi = 0; mi < 2; ++mi) {
        int rbase = wm * 32 + mi * 16 + ((lane >> 4) << 2);
        #pragma unroll
        for (int rr = 0; rr < 4; ++rr) {
          int row = rbase + rr;
          if (row < cnt) {
            int tok = perm[base + row];
            size_t oi = (size_t)tok * DDIM + n;
            out[oi] = x[oi] + alpha * (acc[mi][nj][rr] + bv);
          }
        }
      }
    }
  }
}

// L2-normalize each 768-row of out in place; one wave per token
__global__ __launch_bounds__(256)
void norm_kernel(float* __restrict__ out) {
  const int wave = threadIdx.x >> 6, lane = threadIdx.x & 63;
  const int tok = (blockIdx.x << 2) + wave;
  float4* p = reinterpret_cast<float4*>(out) + (size_t)tok * 192;
  float4 a = p[lane], b = p[lane + 64], c = p[lane + 128];
  float ss = a.x * a.x + a.y * a.y + a.z * a.z + a.w * a.w
           + b.x * b.x + b.y * b.y + b.z * b.z + b.w * b.w
           + c.x * c.x + c.y * c.y + c.z * c.z + c.w * c.w;
  #pragma unroll
  for (int off = 32; off; off >>= 1) ss += __shfl_xor(ss, off);
  const float s = 1.0f / fmaxf(sqrtf(ss), 1e-12f);
  a.x *= s; a.y *= s; a.z *= s; a.w *= s;
  b.x *= s; b.y *= s; b.z *= s; b.w *= s;
  c.x *= s; c.y *= s; c.z *= s; c.w *= s;
  p[lane] = a; p[lane + 64] = b; p[lane + 128] = c;
}

// ---------------- launch ----------------

extern "C" void kernel_launch(void* const* d_in, const int* in_sizes, int n_in,
                              void* d_out, int out_size, void* d_ws, size_t ws_size,
                              hipStream_t stream) {
  const float* x      = (const float*)d_in[0];
  const int*   ids    = (const int*)d_in[1];
  const float* W1     = (const float*)d_in[2];
  const float* b1     = (const float*)d_in[3];
  const float* W2     = (const float*)d_in[4];
  const float* b2     = (const float*)d_in[5];
  const float* ralpha = (const float*)d_in[6];
  const int*   ev2g   = (const int*)d_in[7];
  float* out = (float*)d_out;
  char* ws = (char*)d_ws;

  unsigned short* w1t = (unsigned short*)(ws);                 // [6][1536][768] bf16
  unsigned short* w2t = (unsigned short*)(ws + 14155776);      // [6][768][1536] bf16
  unsigned short* xg  = (unsigned short*)(ws + 28311552);      // [4224][768]  bf16
  unsigned short* h   = (unsigned short*)(ws + 34799616);      // [4224][1536] bf16
  int* perm = (int*)(ws + 47775744);
  int* meta = (int*)(ws + 47808512);

  prep_kernel<<<dim3(24, 12, 13), 256, 0, stream>>>(W1, W2, w1t, w2t, ids, ev2g, perm, meta);
  xgather_kernel<<<1024, 256, 0, stream>>>(x, perm, xg);
  // pass1: h = relu(xg @ W1 + b1)   M=4096 grouped, N=1536, K=768
  gemm_kernel<DDIM, 12, false><<<MAXTILES * 12, 256, 0, stream>>>(
      xg, w1t, b1, meta, perm, x, ralpha, h, out);
  // pass2: out = x + alpha*(h @ W2 + b2)  M=4096 grouped, N=768, K=1536
  gemm_kernel<HDIM, 6, true><<<MAXTILES * 6, 256, 0, stream>>>(
      h, w2t, b2, meta, perm, x, ralpha, nullptr, out);
  norm_kernel<<<1024, 256, 0, stream>>>(out);
}